// Round 3
// baseline (1115.432 us; speedup 1.0000x reference)
//
#include <hip/hip_runtime.h>

// DeepSeek MoE gate. Round 3: split-K=2 register-B GEMM (f16 split-precision,
// 3 MFMA passes) writing f32 partial logits to ws, + tiny epilogue kernel
// (sum halves -> sigmoid+bias -> group-limited top-k).
// Grid 1024 = 4 WGs/CU resident (launch_bounds 256,4 => VGPR<=128, 16 waves/CU).
// XCD swizzle: slice 0 -> XCDs 0-3, slice 1 -> XCDs 4-7 so each XCD's
// B-fragment working set (3.67 MB) fits its private 4 MB L2.

#define TTOK 16384
#define EEXP 256
#define HDIM 7168
#define BM 32
#define BK 128
#define SPLITK 2
#define KSLICE (HDIM / SPLITK)   // 3584
#define NSTEP (KSLICE / BK)      // 28
#define NTHR 256
#define NKC (HDIM / 32)          // 224 k-chunks of 32
#define KCPS (NKC / SPLITK)      // 112 kc per slice
#define GATE_LDS 16384           // A hi 8K + A lo 8K
#define EPI_LDS (64 * 257 * 4)   // 65792

typedef __attribute__((ext_vector_type(4))) float f32x4;
typedef __attribute__((ext_vector_type(4))) _Float16 h4;
typedef __attribute__((ext_vector_type(8))) _Float16 h8;

// ---------------------------------------------------------------------------
// Kernel 1: W[256][7168] f32 -> fragment-major f16 hi/lo tables.
// Wf[eb][kc][lane] holds 8 f16: expert = eb*16 + (lane&15),
// k = kc*32 + (lane>>4)*8 + j  — exactly the 16x16x32 MFMA B-fragment.
// ---------------------------------------------------------------------------
__global__ __launch_bounds__(64) void pack_w_kernel(const float* __restrict__ W,
                                                    _Float16* __restrict__ whi,
                                                    _Float16* __restrict__ wlo) {
  const int kc = blockIdx.x;     // 0..223
  const int eb = blockIdx.y;     // 0..15
  const int lane = threadIdx.x;  // 0..63
  const int e = eb * 16 + (lane & 15);
  const int k0 = kc * 32 + (lane >> 4) * 8;
  const float* src = W + (size_t)e * HDIM + k0;
  h8 hi, lo;
#pragma unroll
  for (int j = 0; j < 8; ++j) {
    float x = src[j];
    _Float16 h = (_Float16)x;
    hi[j] = h;
    lo[j] = (_Float16)((x - (float)h) * 2048.0f);  // exact residual, out of denormal range
  }
  const size_t fi = ((size_t)(eb * NKC + kc) * 64 + lane) * 8;
  *(h8*)(whi + fi) = hi;
  *(h8*)(wlo + fi) = lo;
}

// ---------------------------------------------------------------------------
// Kernel 2: split-K GEMM. One WG = 32 tokens x 256 experts x 3584 K.
// 4 waves, each owns a 64-expert stripe. Writes f32 partial logits.
// ---------------------------------------------------------------------------
__global__ __launch_bounds__(NTHR, 4) void gate_kernel(
    const float* __restrict__ X, const _Float16* __restrict__ Whi,
    const _Float16* __restrict__ Wlo, float* __restrict__ part) {
  extern __shared__ char smem[];
  _Float16* Ahi = (_Float16*)smem;           // [32][128] f16, chunk-swizzled
  _Float16* Alo = (_Float16*)(smem + 8192);  // [32][128]

  // XCD-slice swizzle: bid%8 in {0..3} -> slice 0, {4..7} -> slice 1.
  const int bid = blockIdx.x;
  const int slice = (bid & 7) >> 2;                  // 0..1
  const int tb = ((bid >> 3) << 2) | (bid & 3);      // 0..511
  const int tok0 = tb * BM;
  const int kbase = slice * KSLICE;
  const int kcbase = slice * KCPS;

  const int tid = threadIdx.x;
  const int lane = tid & 63;
  const int wid = tid >> 6;    // 0..3 : 64-expert stripe
  const int webase = wid * 4;  // expert-block (of 16) base

  f32x4 ra[4];         // staged A (f32)
  h8 bh0[4], bl0[4];   // B fragment ping
  h8 bh1[4], bl1[4];   // B fragment pong

  f32x4 acc1[2][4], acc2[2][4];
#pragma unroll
  for (int m = 0; m < 2; ++m)
#pragma unroll
    for (int n = 0; n < 4; ++n) {
      acc1[m][n] = (f32x4){0.f, 0.f, 0.f, 0.f};
      acc2[m][n] = (f32x4){0.f, 0.f, 0.f, 0.f};
    }

  auto LOADA = [&](int k0) {
#pragma unroll
    for (int i = 0; i < 4; ++i) {
      const int p = tid + i * 256;  // f32x4 id; row = p>>5, quad q = p&31
      ra[i] = *(const f32x4*)(X + (size_t)(tok0 + (p >> 5)) * HDIM + k0 + (p & 31) * 4);
    }
  };

  auto STOREA = [&]() {
#pragma unroll
    for (int i = 0; i < 4; ++i) {
      const int p = tid + i * 256;
      const int row = p >> 5, q = p & 31;
      h4 hi, lo;
#pragma unroll
      for (int j = 0; j < 4; ++j) {
        float x = ra[i][j];
        _Float16 h = (_Float16)x;
        hi[j] = h;
        lo[j] = (_Float16)((x - (float)h) * 2048.0f);
      }
      const int ix = row * BK + (((q >> 1) ^ (row & 15)) << 3) + (q & 1) * 4;
      *(h4*)(Ahi + ix) = hi;
      *(h4*)(Alo + ix) = lo;
    }
  };

#define BLOAD(BH, BL, KC)                                              \
  {                                                                    \
    const int kc_ = (KC);                                              \
    _Pragma("unroll") for (int n = 0; n < 4; ++n) {                    \
      const long fi_ = ((long)(webase + n) * NKC + kc_) * 64 + lane;   \
      BH[n] = *(const h8*)(Whi + fi_ * 8);                             \
      BL[n] = *(const h8*)(Wlo + fi_ * 8);                             \
    }                                                                  \
  }

#define PHASE(S, BH, BL)                                                        \
  {                                                                             \
    h8 ah[2], al[2];                                                            \
    _Pragma("unroll") for (int m = 0; m < 2; ++m) {                             \
      const int r_ = m * 16 + (lane & 15);                                      \
      const int cc_ = (S) * 4 + (lane >> 4);                                    \
      const int ix_ = r_ * BK + ((cc_ ^ (r_ & 15)) << 3);                       \
      ah[m] = *(h8*)(Ahi + ix_);                                                \
      al[m] = *(h8*)(Alo + ix_);                                                \
    }                                                                           \
    _Pragma("unroll") for (int n = 0; n < 4; ++n)                               \
        _Pragma("unroll") for (int m = 0; m < 2; ++m) {                         \
      acc1[m][n] = __builtin_amdgcn_mfma_f32_16x16x32_f16(ah[m], BH[n], acc1[m][n], 0, 0, 0); \
      acc2[m][n] = __builtin_amdgcn_mfma_f32_16x16x32_f16(ah[m], BL[n], acc2[m][n], 0, 0, 0); \
      acc2[m][n] = __builtin_amdgcn_mfma_f32_16x16x32_f16(al[m], BH[n], acc2[m][n], 0, 0, 0); \
    }                                                                           \
  }

  LOADA(kbase);
  BLOAD(bh0, bl0, kcbase);
#pragma unroll 1
  for (int kk = 0; kk < NSTEP; ++kk) {
    __syncthreads();  // previous compute's A ds_reads done
    STOREA();
    __syncthreads();
    if (kk + 1 < NSTEP) LOADA(kbase + (kk + 1) * BK);
    const int kcb = kcbase + kk * 4;
    BLOAD(bh1, bl1, kcb + 1);
    PHASE(0, bh0, bl0);
    BLOAD(bh0, bl0, kcb + 2);
    PHASE(1, bh1, bl1);
    BLOAD(bh1, bl1, kcb + 3);
    PHASE(2, bh0, bl0);
    if (kk + 1 < NSTEP) { BLOAD(bh0, bl0, kcb + 4); }
    PHASE(3, bh1, bl1);
  }

  // Write f32 partial logits: part[slice][token][expert].
  // C/D layout: col = lane&15, row = (lane>>4)*4 + reg.
  float* pbase = part + ((long)slice * TTOK + tok0) * EEXP;
  const int ebase = wid * 64;
#pragma unroll
  for (int m = 0; m < 2; ++m)
#pragma unroll
    for (int n = 0; n < 4; ++n) {
      const int e = ebase + n * 16 + (lane & 15);
      const int t0 = m * 16 + (lane >> 4) * 4;
#pragma unroll
      for (int r = 0; r < 4; ++r)
        pbase[(long)(t0 + r) * EEXP + e] = acc1[m][n][r] + acc2[m][n][r] * (1.0f / 2048.0f);
    }
}

// ---------------------------------------------------------------------------
// Kernel 3: epilogue. 64 tokens/WG: sum 2 partials, sigmoid+bias -> LDS,
// then 64 lanes do per-token group-limited top-k.
// ---------------------------------------------------------------------------
__global__ __launch_bounds__(256) void epilogue_kernel(
    const float* __restrict__ part, const float* __restrict__ bias,
    float* __restrict__ outw, float* __restrict__ outi) {
  extern __shared__ float sc[];  // [64][257]
  const int tid = threadIdx.x;
  const long t0 = (long)blockIdx.x * 64;

  const int e4 = (tid & 63) * 4;  // col base (f32x4)
  const int rsub = tid >> 6;      // 0..3
  const f32x4 bv = *(const f32x4*)(bias + e4);
#pragma unroll
  for (int rr = 0; rr < 16; ++rr) {
    const int row = rr * 4 + rsub;
    const f32x4 a = *(const f32x4*)(part + (t0 + row) * EEXP + e4);
    const f32x4 c = *(const f32x4*)(part + ((long)TTOK + t0 + row) * EEXP + e4);
#pragma unroll
    for (int j = 0; j < 4; ++j) {
      const float v = a[j] + c[j];
      sc[row * 257 + e4 + j] = 1.0f / (1.0f + expf(-v)) + bv[j];
    }
  }
  __syncthreads();

  if (tid < 64) {
    const float* s = sc + tid * 257;
    float gmax[8];
#pragma unroll
    for (int g = 0; g < 8; ++g) {
      float mx = -1e30f;
      for (int j = 0; j < 32; ++j) mx = fmaxf(mx, s[g * 32 + j]);
      gmax[g] = mx;
    }
    // top-4 groups (strict > keeps lowest index on ties, matching lax.top_k)
    unsigned selmask = 0;
    for (int it = 0; it < 4; ++it) {
      float best = -1e30f;
      int bi = 0;
      for (int g = 0; g < 8; ++g)
        if (!((selmask >> g) & 1) && gmax[g] > best) {
          best = gmax[g];
          bi = g;
        }
      selmask |= 1u << bi;
    }
    // stable top-8 over masked scores (masked-out groups contribute 0.0)
    float vals[8];
    int idx[8];
#pragma unroll
    for (int j = 0; j < 8; ++j) {
      vals[j] = -1e30f;
      idx[j] = 0;
    }
    for (int e = 0; e < 256; ++e) {
      const float v = ((selmask >> (e >> 5)) & 1) ? s[e] : 0.0f;
      if (v > vals[7]) {
        int p = 7;
        while (p > 0 && v > vals[p - 1]) {
          vals[p] = vals[p - 1];
          idx[p] = idx[p - 1];
          --p;
        }
        vals[p] = v;
        idx[p] = e;
      }
    }
    float ssum = 0.0f;
#pragma unroll
    for (int j = 0; j < 8; ++j) ssum += vals[j];
    const float den = ssum + 1e-6f;
    const long tg = t0 + tid;
#pragma unroll
    for (int j = 0; j < 8; ++j) {
      outw[tg * 8 + j] = vals[j] / den;
      outi[tg * 8 + j] = (float)idx[j];  // indices written as f32 values
    }
  }
}

extern "C" void kernel_launch(void* const* d_in, const int* in_sizes, int n_in,
                              void* d_out, int out_size, void* d_ws, size_t ws_size,
                              hipStream_t stream) {
  const float* X = (const float*)d_in[0];     // [16384,7168] f32
  const float* W = (const float*)d_in[1];     // [256,7168] f32
  const float* bias = (const float*)d_in[2];  // [256] f32

  _Float16* whi = (_Float16*)d_ws;                       // 3.67 MB
  _Float16* wlo = whi + (size_t)EEXP * HDIM;             // 3.67 MB
  float* part = (float*)(wlo + (size_t)EEXP * HDIM);     // 2 x 16384 x 256 f32 = 33.6 MB

  float* outw = (float*)d_out;            // [16384,8]
  float* outi = outw + (size_t)TTOK * 8;  // [16384,8] as f32 values

  hipFuncSetAttribute((const void*)epilogue_kernel,
                      hipFuncAttributeMaxDynamicSharedMemorySize, EPI_LDS);

  pack_w_kernel<<<dim3(NKC, EEXP / 16), 64, 0, stream>>>(W, whi, wlo);
  gate_kernel<<<SPLITK * (TTOK / BM), NTHR, GATE_LDS, stream>>>(X, whi, wlo, part);
  epilogue_kernel<<<TTOK / 64, 256, EPI_LDS, stream>>>(part, bias, outw, outi);
}

// Round 4
// 395.335 us; speedup vs baseline: 2.8215x; 2.8215x over previous
//
#include <hip/hip_runtime.h>

// DeepSeek MoE gate, fused: logits GEMM (f16 split-precision, 3 MFMA passes)
// + sigmoid+bias + group-limited top-k epilogue.
// Round 4 = Round 2 structure (BM=32, 4 waves, B-fragments from L2, A via LDS)
// with the latency fixes:
//  - B prefetch 2 k-phases deep (4 rotating reg buffers, ~128 VGPRs)
//  - raw s_barrier instead of __syncthreads so B loads stay in flight across
//    the K-step barrier (counted vmcnt, T4); writer-side lgkmcnt(0) only
//  - s_setprio(1) around MFMA clusters (T5)
//  - __launch_bounds__(256,2): allocator budget 256 VGPR, no forced squeeze

#define TTOK 16384
#define EEXP 256
#define HDIM 7168
#define BM 32
#define BK 128
#define NSTEP (HDIM / BK)   // 56
#define NTHR 256
#define NKC (HDIM / 32)     // 224 k-chunks of 32
#define LDS_BYTES 33024     // max(A hi+lo 16K, scores 32x257x4 = 32896)

typedef __attribute__((ext_vector_type(4))) float f32x4;
typedef __attribute__((ext_vector_type(4))) _Float16 h4;
typedef __attribute__((ext_vector_type(8))) _Float16 h8;

#define BAR_ONLY() asm volatile("s_barrier" ::: "memory")
#define LGKM0_BAR()                                     \
  do {                                                  \
    asm volatile("s_waitcnt lgkmcnt(0)" ::: "memory");  \
    asm volatile("s_barrier" ::: "memory");             \
  } while (0)

// ---------------------------------------------------------------------------
// Kernel 1: W[256][7168] f32 -> fragment-major f16 hi/lo tables.
// Wf[eb][kc][lane] holds 8 f16: expert = eb*16 + (lane&15),
// k = kc*32 + (lane>>4)*8 + j  — exactly the 16x16x32 MFMA B-fragment.
// ---------------------------------------------------------------------------
__global__ __launch_bounds__(64) void pack_w_kernel(const float* __restrict__ W,
                                                    _Float16* __restrict__ whi,
                                                    _Float16* __restrict__ wlo) {
  const int kc = blockIdx.x;     // 0..223
  const int eb = blockIdx.y;     // 0..15
  const int lane = threadIdx.x;  // 0..63
  const int e = eb * 16 + (lane & 15);
  const int k0 = kc * 32 + (lane >> 4) * 8;
  const float* src = W + (size_t)e * HDIM + k0;
  h8 hi, lo;
#pragma unroll
  for (int j = 0; j < 8; ++j) {
    float x = src[j];
    _Float16 h = (_Float16)x;
    hi[j] = h;
    lo[j] = (_Float16)((x - (float)h) * 2048.0f);  // exact residual, out of denormals
  }
  const size_t fi = ((size_t)(eb * NKC + kc) * 64 + lane) * 8;
  *(h8*)(whi + fi) = hi;
  *(h8*)(wlo + fi) = lo;
}

// ---------------------------------------------------------------------------
// Kernel 2: fused gate. One WG = 32 tokens x 256 experts. 4 waves (1x4).
// ---------------------------------------------------------------------------
__global__ __launch_bounds__(NTHR, 2) void gate_kernel(
    const float* __restrict__ X, const _Float16* __restrict__ Whi,
    const _Float16* __restrict__ Wlo, const float* __restrict__ bias,
    float* __restrict__ outw, float* __restrict__ outi) {
  extern __shared__ char smem[];
  _Float16* Ahi = (_Float16*)smem;           // [32][128] f16, chunk-swizzled
  _Float16* Alo = (_Float16*)(smem + 8192);  // [32][128]
  float (*scores)[EEXP + 1] = (float (*)[EEXP + 1])smem;  // [32][257], overlays A

  const int tid = threadIdx.x;
  const int lane = tid & 63;
  const int wid = tid >> 6;    // 0..3 : 64-expert stripe
  const int webase = wid * 4;  // expert-block (of 16) base
  const int tok0 = blockIdx.x * BM;

  f32x4 ra[4];                      // staged A (f32)
  h8 bh0[4], bl0[4];                // B fragment buffers, 2-phase-deep rotation
  h8 bh1[4], bl1[4];
  h8 bh2[4], bl2[4];
  h8 bh3[4], bl3[4];

  f32x4 acc1[2][4], acc2[2][4];
#pragma unroll
  for (int m = 0; m < 2; ++m)
#pragma unroll
    for (int n = 0; n < 4; ++n) {
      acc1[m][n] = (f32x4){0.f, 0.f, 0.f, 0.f};
      acc2[m][n] = (f32x4){0.f, 0.f, 0.f, 0.f};
    }

  auto LOADA = [&](int k0) {
#pragma unroll
    for (int i = 0; i < 4; ++i) {
      const int p = tid + i * 256;  // f32x4 id; row = p>>5, quad q = p&31
      ra[i] = *(const f32x4*)(X + (size_t)(tok0 + (p >> 5)) * HDIM + k0 + (p & 31) * 4);
    }
  };

  auto STOREA = [&]() {
#pragma unroll
    for (int i = 0; i < 4; ++i) {
      const int p = tid + i * 256;
      const int row = p >> 5, q = p & 31;
      h4 hi, lo;
#pragma unroll
      for (int j = 0; j < 4; ++j) {
        float x = ra[i][j];
        _Float16 h = (_Float16)x;
        hi[j] = h;
        lo[j] = (_Float16)((x - (float)h) * 2048.0f);
      }
      // 16B chunk cc = q>>1 (0..15), swizzle: cc ^= row&15 (row stride 256B)
      const int ix = row * BK + (((q >> 1) ^ (row & 15)) << 3) + (q & 1) * 4;
      *(h4*)(Ahi + ix) = hi;
      *(h4*)(Alo + ix) = lo;
    }
  };

#define BLOAD(BH, BL, KC)                                              \
  {                                                                    \
    const int kc_ = (KC);                                              \
    _Pragma("unroll") for (int n = 0; n < 4; ++n) {                    \
      const long fi_ = ((long)(webase + n) * NKC + kc_) * 64 + lane;   \
      BH[n] = *(const h8*)(Whi + fi_ * 8);                             \
      BL[n] = *(const h8*)(Wlo + fi_ * 8);                             \
    }                                                                  \
  }

#define PHASE(S, BH, BL)                                                        \
  {                                                                             \
    h8 ah[2], al[2];                                                            \
    _Pragma("unroll") for (int m = 0; m < 2; ++m) {                             \
      const int r_ = m * 16 + (lane & 15);                                      \
      const int cc_ = (S) * 4 + (lane >> 4);                                    \
      const int ix_ = r_ * BK + ((cc_ ^ (r_ & 15)) << 3);                       \
      ah[m] = *(h8*)(Ahi + ix_);                                                \
      al[m] = *(h8*)(Alo + ix_);                                                \
    }                                                                           \
    __builtin_amdgcn_s_setprio(1);                                              \
    _Pragma("unroll") for (int n = 0; n < 4; ++n)                               \
        _Pragma("unroll") for (int m = 0; m < 2; ++m) {                         \
      acc1[m][n] = __builtin_amdgcn_mfma_f32_16x16x32_f16(ah[m], BH[n], acc1[m][n], 0, 0, 0); \
      acc2[m][n] = __builtin_amdgcn_mfma_f32_16x16x32_f16(ah[m], BL[n], acc2[m][n], 0, 0, 0); \
      acc2[m][n] = __builtin_amdgcn_mfma_f32_16x16x32_f16(al[m], BH[n], acc2[m][n], 0, 0, 0); \
    }                                                                           \
    __builtin_amdgcn_s_setprio(0);                                              \
  }

  LOADA(0);
  BLOAD(bh0, bl0, 0);
  BLOAD(bh1, bl1, 1);
#pragma unroll 1
  for (int kk = 0; kk < NSTEP; ++kk) {
    // All waves' A ds_reads of the previous step are consumed by their MFMAs
    // (compiler-inserted lgkmcnt), so a plain barrier suffices before overwrite.
    BAR_ONLY();
    STOREA();        // compiler emits counted vmcnt here: retires ra, keeps B loads in flight
    LGKM0_BAR();     // writer-side drain of ds_writes, then barrier
    if (kk + 1 < NSTEP) LOADA((kk + 1) * BK);
    const int kcb = kk * 4;
    BLOAD(bh2, bl2, kcb + 2);
    PHASE(0, bh0, bl0);
    BLOAD(bh3, bl3, kcb + 3);
    PHASE(1, bh1, bl1);
    if (kk + 1 < NSTEP) { BLOAD(bh0, bl0, kcb + 4); }  // crosses next barrier in flight
    PHASE(2, bh2, bl2);
    if (kk + 1 < NSTEP) { BLOAD(bh1, bl1, kcb + 5); }
    PHASE(3, bh3, bl3);
  }

  LGKM0_BAR();  // last A reads done before scores overlay staging LDS

  // scores = sigmoid(logit) + bias  -> LDS [32][257]
  // C/D layout: col = lane&15, row = (lane>>4)*4 + reg
  const int ebase = wid * 64;
#pragma unroll
  for (int m = 0; m < 2; ++m)
#pragma unroll
    for (int n = 0; n < 4; ++n) {
      const int e = ebase + n * 16 + (lane & 15);
      const float b = bias[e];
      const int t0 = m * 16 + (lane >> 4) * 4;
#pragma unroll
      for (int r = 0; r < 4; ++r) {
        const float logit = acc1[m][n][r] + acc2[m][n][r] * (1.0f / 2048.0f);
        scores[t0 + r][e] = 1.0f / (1.0f + expf(-logit)) + b;
      }
    }
  __syncthreads();

  // Per-token top-k: 8 tokens per wave, one active lane per token (32 total).
  if ((lane & 7) == 0) {
    const int t = wid * 8 + (lane >> 3);  // 0..31
    const float* sc = scores[t];

    float gmax[8];
#pragma unroll
    for (int g = 0; g < 8; ++g) {
      float mx = -1e30f;
      for (int j = 0; j < 32; ++j) mx = fmaxf(mx, sc[g * 32 + j]);
      gmax[g] = mx;
    }
    // top-4 groups (strict > keeps lowest index on ties, matching lax.top_k)
    unsigned selmask = 0;
    for (int it = 0; it < 4; ++it) {
      float best = -1e30f;
      int bi = 0;
      for (int g = 0; g < 8; ++g)
        if (!((selmask >> g) & 1) && gmax[g] > best) {
          best = gmax[g];
          bi = g;
        }
      selmask |= 1u << bi;
    }
    // stable top-8 over masked scores (masked-out groups contribute 0.0)
    float vals[8];
    int idx[8];
#pragma unroll
    for (int j = 0; j < 8; ++j) {
      vals[j] = -1e30f;
      idx[j] = 0;
    }
    for (int e = 0; e < 256; ++e) {
      const float v = ((selmask >> (e >> 5)) & 1) ? sc[e] : 0.0f;
      if (v > vals[7]) {
        int p = 7;
        while (p > 0 && v > vals[p - 1]) {
          vals[p] = vals[p - 1];
          idx[p] = idx[p - 1];
          --p;
        }
        vals[p] = v;
        idx[p] = e;
      }
    }
    float ssum = 0.0f;
#pragma unroll
    for (int j = 0; j < 8; ++j) ssum += vals[j];
    const float den = ssum + 1e-6f;
    const long tg = (long)tok0 + t;
#pragma unroll
    for (int j = 0; j < 8; ++j) {
      outw[tg * 8 + j] = vals[j] / den;
      outi[tg * 8 + j] = (float)idx[j];  // indices written as f32 values
    }
  }
}

extern "C" void kernel_launch(void* const* d_in, const int* in_sizes, int n_in,
                              void* d_out, int out_size, void* d_ws, size_t ws_size,
                              hipStream_t stream) {
  const float* X = (const float*)d_in[0];     // [16384,7168] f32
  const float* W = (const float*)d_in[1];     // [256,7168] f32
  const float* bias = (const float*)d_in[2];  // [256] f32

  _Float16* whi = (_Float16*)d_ws;            // 3.67 MB
  _Float16* wlo = whi + (size_t)EEXP * HDIM;  // 3.67 MB

  float* outw = (float*)d_out;            // [16384,8]
  float* outi = outw + (size_t)TTOK * 8;  // [16384,8] as f32 values

  hipFuncSetAttribute((const void*)gate_kernel,
                      hipFuncAttributeMaxDynamicSharedMemorySize, LDS_BYTES);

  pack_w_kernel<<<dim3(NKC, EEXP / 16), 64, 0, stream>>>(W, whi, wlo);
  gate_kernel<<<TTOK / BM, NTHR, LDS_BYTES, stream>>>(X, whi, wlo, bias, outw, outi);
}

// Round 5
// 357.657 us; speedup vs baseline: 3.1187x; 1.1053x over previous
//
#include <hip/hip_runtime.h>

// DeepSeek MoE gate, fused: logits GEMM (f16 split-precision, 3 MFMA passes)
// + sigmoid+bias + group-limited top-k epilogue.
// Round 5: BM=64, 8 waves, each wave owns a DISTINCT 32-expert stripe
// (no duplicate B loads) -> B L2 traffic halves to 1.88 GB (55 us floor);
// MFMA becomes the critical resource (3725 cyc/step vs B 2285 / A-LDS 2250 /
// X-HBM 3280). B fragments from L2, 4-phase-deep register rotation crossing
// raw s_barriers (counted vmcnt). launch_bounds(512,1): no forced reg cap,
// grid 256 = 1 WG/CU so occupancy doesn't matter, spill does.

#define TTOK 16384
#define EEXP 256
#define HDIM 7168
#define BM 64
#define BK 128
#define NSTEP (HDIM / BK)   // 56
#define NTHR 512
#define NKC (HDIM / 32)     // 224 k-chunks of 32
#define LDS_BYTES 65792     // scores [64][257] f32; GEMM phase uses 32K (A hi/lo)

typedef __attribute__((ext_vector_type(4))) float f32x4;
typedef __attribute__((ext_vector_type(4))) _Float16 h4;
typedef __attribute__((ext_vector_type(8))) _Float16 h8;

#define BAR_ONLY() asm volatile("s_barrier" ::: "memory")
#define LGKM0_BAR()                                     \
  do {                                                  \
    asm volatile("s_waitcnt lgkmcnt(0)" ::: "memory");  \
    asm volatile("s_barrier" ::: "memory");             \
  } while (0)

// ---------------------------------------------------------------------------
// Kernel 1: W[256][7168] f32 -> fragment-major f16 hi/lo tables.
// Wf[eb][kc][lane] holds 8 f16: expert = eb*16 + (lane&15),
// k = kc*32 + (lane>>4)*8 + j  — exactly the 16x16x32 MFMA B-fragment.
// ---------------------------------------------------------------------------
__global__ __launch_bounds__(64) void pack_w_kernel(const float* __restrict__ W,
                                                    _Float16* __restrict__ whi,
                                                    _Float16* __restrict__ wlo) {
  const int kc = blockIdx.x;     // 0..223
  const int eb = blockIdx.y;     // 0..15
  const int lane = threadIdx.x;  // 0..63
  const int e = eb * 16 + (lane & 15);
  const int k0 = kc * 32 + (lane >> 4) * 8;
  const float* src = W + (size_t)e * HDIM + k0;
  h8 hi, lo;
#pragma unroll
  for (int j = 0; j < 8; ++j) {
    float x = src[j];
    _Float16 h = (_Float16)x;
    hi[j] = h;
    lo[j] = (_Float16)((x - (float)h) * 2048.0f);  // exact residual, out of denormals
  }
  const size_t fi = ((size_t)(eb * NKC + kc) * 64 + lane) * 8;
  *(h8*)(whi + fi) = hi;
  *(h8*)(wlo + fi) = lo;
}

// ---------------------------------------------------------------------------
// Kernel 2: fused gate. One WG = 64 tokens x 256 experts. 8 waves, each a
// 32-expert stripe x all 64 tokens (m=4 x n=2 fragments).
// ---------------------------------------------------------------------------
__global__ __launch_bounds__(NTHR, 1) void gate_kernel(
    const float* __restrict__ X, const _Float16* __restrict__ Whi,
    const _Float16* __restrict__ Wlo, const float* __restrict__ bias,
    float* __restrict__ outw, float* __restrict__ outi) {
  extern __shared__ char smem[];
  _Float16* Ahi = (_Float16*)smem;            // [64][128] f16, chunk-swizzled
  _Float16* Alo = (_Float16*)(smem + 16384);  // [64][128]
  float (*scores)[EEXP + 1] = (float (*)[EEXP + 1])smem;  // [64][257], overlays A

  const int tid = threadIdx.x;
  const int lane = tid & 63;
  const int wid = tid >> 6;    // 0..7 : 32-expert stripe
  const int webase = wid * 2;  // expert-block (of 16) base
  const int tok0 = blockIdx.x * BM;

  f32x4 ra[4];  // staged A (f32)
  // B fragment buffers: 4-phase-deep rotation, 2 expert-blocks each.
  h8 bh0[2], bl0[2], bh1[2], bl1[2], bh2[2], bl2[2], bh3[2], bl3[2];

  f32x4 acc1[4][2], acc2[4][2];
#pragma unroll
  for (int m = 0; m < 4; ++m)
#pragma unroll
    for (int n = 0; n < 2; ++n) {
      acc1[m][n] = (f32x4){0.f, 0.f, 0.f, 0.f};
      acc2[m][n] = (f32x4){0.f, 0.f, 0.f, 0.f};
    }

  auto LOADA = [&](int k0) {
#pragma unroll
    for (int i = 0; i < 4; ++i) {
      const int p = tid + i * 512;  // f32x4 id; row = p>>5 (0..63), quad q = p&31
      ra[i] = *(const f32x4*)(X + (size_t)(tok0 + (p >> 5)) * HDIM + k0 + (p & 31) * 4);
    }
  };

  auto STOREA = [&]() {
#pragma unroll
    for (int i = 0; i < 4; ++i) {
      const int p = tid + i * 512;
      const int row = p >> 5, q = p & 31;
      h4 hi, lo;
#pragma unroll
      for (int j = 0; j < 4; ++j) {
        float x = ra[i][j];
        _Float16 h = (_Float16)x;
        hi[j] = h;
        lo[j] = (_Float16)((x - (float)h) * 2048.0f);
      }
      // 16B chunk cc = q>>1 (0..15), swizzle: cc ^= row&15 (row stride 256B)
      const int ix = row * BK + (((q >> 1) ^ (row & 15)) << 3) + (q & 1) * 4;
      *(h4*)(Ahi + ix) = hi;
      *(h4*)(Alo + ix) = lo;
    }
  };

#define BLOAD(BH, BL, KC)                                              \
  {                                                                    \
    const int kc_ = (KC);                                              \
    _Pragma("unroll") for (int n = 0; n < 2; ++n) {                    \
      const long fi_ = ((long)(webase + n) * NKC + kc_) * 64 + lane;   \
      BH[n] = *(const h8*)(Whi + fi_ * 8);                             \
      BL[n] = *(const h8*)(Wlo + fi_ * 8);                             \
    }                                                                  \
  }

#define PHASE(S, BH, BL)                                                        \
  {                                                                             \
    h8 ah[4], al[4];                                                            \
    _Pragma("unroll") for (int m = 0; m < 4; ++m) {                             \
      const int r_ = m * 16 + (lane & 15);                                      \
      const int cc_ = (S) * 4 + (lane >> 4);                                    \
      const int ix_ = r_ * BK + ((cc_ ^ (r_ & 15)) << 3);                       \
      ah[m] = *(h8*)(Ahi + ix_);                                                \
      al[m] = *(h8*)(Alo + ix_);                                                \
    }                                                                           \
    __builtin_amdgcn_s_setprio(1);                                              \
    _Pragma("unroll") for (int n = 0; n < 2; ++n)                               \
        _Pragma("unroll") for (int m = 0; m < 4; ++m) {                         \
      acc1[m][n] = __builtin_amdgcn_mfma_f32_16x16x32_f16(ah[m], BH[n], acc1[m][n], 0, 0, 0); \
      acc2[m][n] = __builtin_amdgcn_mfma_f32_16x16x32_f16(ah[m], BL[n], acc2[m][n], 0, 0, 0); \
      acc2[m][n] = __builtin_amdgcn_mfma_f32_16x16x32_f16(al[m], BH[n], acc2[m][n], 0, 0, 0); \
    }                                                                           \
    __builtin_amdgcn_s_setprio(0);                                              \
  }

  LOADA(0);
  BLOAD(bh0, bl0, 0);
  BLOAD(bh1, bl1, 1);
  BLOAD(bh2, bl2, 2);
  BLOAD(bh3, bl3, 3);
#pragma unroll 1
  for (int kk = 0; kk < NSTEP; ++kk) {
    // Previous step's A ds_reads were consumed by MFMAs (compiler lgkm waits),
    // so a plain barrier suffices before overwriting the A tile.
    BAR_ONLY();
    STOREA();     // vmcnt wait here retires only ra; B loads stay in flight
    LGKM0_BAR();  // writer-side drain of ds_writes, then barrier
    if (kk + 1 < NSTEP) LOADA((kk + 1) * BK);
    const int kcb = kk * 4;
    const bool pf = (kk + 1 < NSTEP);
    PHASE(0, bh0, bl0);
    if (pf) { BLOAD(bh0, bl0, kcb + 4); }  // crosses next barrier in flight
    PHASE(1, bh1, bl1);
    if (pf) { BLOAD(bh1, bl1, kcb + 5); }
    PHASE(2, bh2, bl2);
    if (pf) { BLOAD(bh2, bl2, kcb + 6); }
    PHASE(3, bh3, bl3);
    if (pf) { BLOAD(bh3, bl3, kcb + 7); }
  }

  __syncthreads();  // full drain before scores overlay the staging LDS

  // scores = sigmoid(logit) + bias  -> LDS [64][257]
  // C/D layout: col = lane&15, row = (lane>>4)*4 + reg
#pragma unroll
  for (int m = 0; m < 4; ++m)
#pragma unroll
    for (int n = 0; n < 2; ++n) {
      const int e = wid * 32 + n * 16 + (lane & 15);
      const float b = bias[e];
      const int t0 = m * 16 + (lane >> 4) * 4;
#pragma unroll
      for (int r = 0; r < 4; ++r) {
        const float logit = acc1[m][n][r] + acc2[m][n][r] * (1.0f / 2048.0f);
        scores[t0 + r][e] = 1.0f / (1.0f + expf(-logit)) + b;
      }
    }
  __syncthreads();

  // Per-token top-k: 8 tokens per wave, one active lane per token (64 total).
  if ((lane & 7) == 0) {
    const int t = wid * 8 + (lane >> 3);  // 0..63
    const float* sc = scores[t];

    float gmax[8];
#pragma unroll
    for (int g = 0; g < 8; ++g) {
      float mx = -1e30f;
      for (int j = 0; j < 32; ++j) mx = fmaxf(mx, sc[g * 32 + j]);
      gmax[g] = mx;
    }
    // top-4 groups (strict > keeps lowest index on ties, matching lax.top_k)
    unsigned selmask = 0;
    for (int it = 0; it < 4; ++it) {
      float best = -1e30f;
      int bi = 0;
      for (int g = 0; g < 8; ++g)
        if (!((selmask >> g) & 1) && gmax[g] > best) {
          best = gmax[g];
          bi = g;
        }
      selmask |= 1u << bi;
    }
    // stable top-8 over masked scores (masked-out groups contribute 0.0)
    float vals[8];
    int idx[8];
#pragma unroll
    for (int j = 0; j < 8; ++j) {
      vals[j] = -1e30f;
      idx[j] = 0;
    }
    for (int e = 0; e < 256; ++e) {
      const float v = ((selmask >> (e >> 5)) & 1) ? sc[e] : 0.0f;
      if (v > vals[7]) {
        int p = 7;
        while (p > 0 && v > vals[p - 1]) {
          vals[p] = vals[p - 1];
          idx[p] = idx[p - 1];
          --p;
        }
        vals[p] = v;
        idx[p] = e;
      }
    }
    float ssum = 0.0f;
#pragma unroll
    for (int j = 0; j < 8; ++j) ssum += vals[j];
    const float den = ssum + 1e-6f;
    const long tg = (long)tok0 + t;
#pragma unroll
    for (int j = 0; j < 8; ++j) {
      outw[tg * 8 + j] = vals[j] / den;
      outi[tg * 8 + j] = (float)idx[j];  // indices written as f32 values
    }
  }
}

extern "C" void kernel_launch(void* const* d_in, const int* in_sizes, int n_in,
                              void* d_out, int out_size, void* d_ws, size_t ws_size,
                              hipStream_t stream) {
  const float* X = (const float*)d_in[0];     // [16384,7168] f32
  const float* W = (const float*)d_in[1];     // [256,7168] f32
  const float* bias = (const float*)d_in[2];  // [256] f32

  _Float16* whi = (_Float16*)d_ws;            // 3.67 MB
  _Float16* wlo = whi + (size_t)EEXP * HDIM;  // 3.67 MB

  float* outw = (float*)d_out;            // [16384,8]
  float* outi = outw + (size_t)TTOK * 8;  // [16384,8] as f32 values

  hipFuncSetAttribute((const void*)gate_kernel,
                      hipFuncAttributeMaxDynamicSharedMemorySize, LDS_BYTES);

  pack_w_kernel<<<dim3(NKC, EEXP / 16), 64, 0, stream>>>(W, whi, wlo);
  gate_kernel<<<TTOK / BM, NTHR, LDS_BYTES, stream>>>(X, whi, wlo, bias, outw, outi);
}

// Round 6
// 285.678 us; speedup vs baseline: 3.9045x; 1.2520x over previous
//
#include <hip/hip_runtime.h>

// DeepSeek MoE gate, fused. Round 6: m97-structure GEMM.
// BM=64 tok x 256 experts, BK=64, 8 waves (2m x 4n), grid 256 (1 WG/CU).
// B (f16 hi/lo split, fragment-major packed blob) staged via
// global_load_lds width=16 into double-buffered LDS (2x64KB) -- result-less
// loads stay in flight across the per-step barrier until the explicit
// vmcnt(0). A (f32->f16 hi/lo convert) reg-staged, double-buffered (2x16KB).
// LDS = 160 KB exactly. One vmcnt(0)+lgkmcnt(0)+s_barrier per K-step.

#define TTOK 16384
#define EEXP 256
#define HDIM 7168
#define BM 64
#define BK 64
#define NSTEP (HDIM / BK)  // 112
#define NTHR 512
#define LDS_BYTES 163840   // B: 2x65536, A: 2x16384
#define ABASE 131072

typedef __attribute__((ext_vector_type(4))) float f32x4;
typedef __attribute__((ext_vector_type(8))) _Float16 h8;

__device__ __forceinline__ void gload_lds16(const void* g, void* l) {
  typedef const __attribute__((address_space(1))) unsigned int gu32;
  typedef __attribute__((address_space(3))) unsigned int lu32;
  __builtin_amdgcn_global_load_lds((gu32*)g, (lu32*)l, 16, 0, 0);
}

// ---------------------------------------------------------------------------
// Kernel 1: W[256][7168] f32 -> fragment-major f16 hi/lo blob, per-K-step
// contiguous. Byte offset = (kcg*32 + eb*2 + hl)*1024 + lane*16, where the
// fragment at [kcg][eb][hl][lane] holds expert e = eb*16+(lane&15),
// k = kcg*32 + (lane>>4)*8 + j (16x16x32 MFMA B-fragment). One K-step
// (kcg pair) = 64 KB contiguous.
// ---------------------------------------------------------------------------
__global__ __launch_bounds__(64) void pack_w_kernel(const float* __restrict__ W,
                                                    _Float16* __restrict__ blob) {
  const int kcg = blockIdx.x;    // 0..223
  const int eb = blockIdx.y;     // 0..15
  const int lane = threadIdx.x;  // 0..63
  const int e = eb * 16 + (lane & 15);
  const int k0 = kcg * 32 + (lane >> 4) * 8;
  const float* src = W + (size_t)e * HDIM + k0;
  h8 hi, lo;
#pragma unroll
  for (int j = 0; j < 8; ++j) {
    float x = src[j];
    _Float16 h = (_Float16)x;
    hi[j] = h;
    lo[j] = (_Float16)((x - (float)h) * 2048.0f);  // exact residual, out of denormals
  }
  char* dst = (char*)blob + ((size_t)kcg * 32 + eb * 2) * 1024 + lane * 16;
  *(h8*)dst = hi;
  *(h8*)(dst + 1024) = lo;
}

// ---------------------------------------------------------------------------
// Kernel 2: fused gate.
// ---------------------------------------------------------------------------
__global__ __launch_bounds__(NTHR, 1) void gate_kernel(
    const float* __restrict__ X, const _Float16* __restrict__ Wblob,
    const float* __restrict__ bias, float* __restrict__ outw,
    float* __restrict__ outi) {
  extern __shared__ char smem[];
  float (*scores)[EEXP + 1] = (float (*)[EEXP + 1])smem;  // epilogue overlay

  const int tid = threadIdx.x;
  const int lane = tid & 63;
  const int wid = tid >> 6;          // 0..7
  const int wr = wid >> 2;           // 0..1 : 32-token stripe
  const int wc = wid & 3;            // 0..3 : 64-expert stripe
  const int tok0 = blockIdx.x * BM;

  // A staging map: thread -> row = tid>>3, k-chunk-of-8 = tid&7
  const int arow = tid >> 3, ac8 = tid & 7;
  const float* asrc = X + (size_t)(tok0 + arow) * HDIM + ac8 * 8;
  const int awoff = arow * 128 + ((ac8 ^ (arow & 7)) << 4);  // bytes in A plane

  f32x4 ra0, ra1;  // A prefetch registers

  f32x4 acc1[2][4], acc2[2][4];
#pragma unroll
  for (int m = 0; m < 2; ++m)
#pragma unroll
    for (int n = 0; n < 4; ++n) {
      acc1[m][n] = (f32x4){0.f, 0.f, 0.f, 0.f};
      acc2[m][n] = (f32x4){0.f, 0.f, 0.f, 0.f};
    }

  auto LOADA = [&](int step) {
    ra0 = *(const f32x4*)(asrc + (size_t)step * BK);
    ra1 = *(const f32x4*)(asrc + (size_t)step * BK + 4);
  };

  // 8 global_load_lds per wave: granule-block gb = i*8 + wid; 64 x 1KB = 64KB.
  auto STAGEB = [&](int step, int buf) {
    const char* gs = (const char*)Wblob + (size_t)step * 65536 + lane * 16;
    char* lb = smem + buf * 65536;
#pragma unroll
    for (int i = 0; i < 8; ++i) {
      const int gb = i * 8 + wid;
      gload_lds16(gs + gb * 1024, lb + gb * 1024);
    }
  };

  auto ACONV = [&](int buf) {
    h8 hi, lo;
#pragma unroll
    for (int j = 0; j < 4; ++j) {
      float x = ra0[j];
      _Float16 h = (_Float16)x;
      hi[j] = h;
      lo[j] = (_Float16)((x - (float)h) * 2048.0f);
      float y = ra1[j];
      _Float16 g = (_Float16)y;
      hi[4 + j] = g;
      lo[4 + j] = (_Float16)((y - (float)g) * 2048.0f);
    }
    char* ab = smem + ABASE + buf * 16384;
    *(h8*)(ab + awoff) = hi;
    *(h8*)(ab + 8192 + awoff) = lo;
  };

#define PHASE(S, BUF)                                                           \
  {                                                                             \
    const char* ab = smem + ABASE + (BUF) * 16384;                              \
    const char* bb = smem + (BUF) * 65536;                                      \
    h8 ah[2], al[2];                                                            \
    _Pragma("unroll") for (int m = 0; m < 2; ++m) {                             \
      const int r_ = wr * 32 + m * 16 + (lane & 15);                            \
      const int ao_ = r_ * 128 + ((((S) * 4 + (lane >> 4)) ^ (lane & 7)) << 4); \
      ah[m] = *(const h8*)(ab + ao_);                                           \
      al[m] = *(const h8*)(ab + 8192 + ao_);                                    \
    }                                                                           \
    h8 bh[4], bl[4];                                                            \
    _Pragma("unroll") for (int n = 0; n < 4; ++n) {                             \
      const int bo_ = (((S) * 16 + (wc * 4 + n)) * 2) * 1024 + lane * 16;       \
      bh[n] = *(const h8*)(bb + bo_);                                           \
      bl[n] = *(const h8*)(bb + bo_ + 1024);                                    \
    }                                                                           \
    _Pragma("unroll") for (int n = 0; n < 4; ++n)                               \
        _Pragma("unroll") for (int m = 0; m < 2; ++m) {                         \
      acc1[m][n] = __builtin_amdgcn_mfma_f32_16x16x32_f16(ah[m], bh[n], acc1[m][n], 0, 0, 0); \
      acc2[m][n] = __builtin_amdgcn_mfma_f32_16x16x32_f16(ah[m], bl[n], acc2[m][n], 0, 0, 0); \
      acc2[m][n] = __builtin_amdgcn_mfma_f32_16x16x32_f16(al[m], bh[n], acc2[m][n], 0, 0, 0); \
    }                                                                           \
  }

  // Prologue: stage step 0 into buffer 0.
  LOADA(0);      // issued BEFORE gloads -> ACONV's auto-wait is counted
  STAGEB(0, 0);
  ACONV(0);
  asm volatile("s_waitcnt vmcnt(0) lgkmcnt(0)" ::: "memory");
  __builtin_amdgcn_s_barrier();

  int buf = 0;
#pragma unroll 1
  for (int kk = 0; kk < NSTEP; ++kk) {
    const bool pf = (kk + 1 < NSTEP);
    if (pf) {
      LOADA(kk + 1);        // 2 loads, oldest in FIFO
      STAGEB(kk + 1, buf ^ 1);  // 8 result-less gloads, stay in flight
    }
    PHASE(0, buf);
    PHASE(1, buf);
    if (pf) ACONV(buf ^ 1);  // waits vmcnt(8): ra only, B gloads still flying
    asm volatile("s_waitcnt vmcnt(0) lgkmcnt(0)" ::: "memory");
    __builtin_amdgcn_s_barrier();
    buf ^= 1;
  }

  // ---- epilogue: scores -> LDS overlay, then per-token group-top-k ----
  // C/D layout: col = lane&15, row = (lane>>4)*4 + reg
#pragma unroll
  for (int m = 0; m < 2; ++m)
#pragma unroll
    for (int n = 0; n < 4; ++n) {
      const int e = (wc * 4 + n) * 16 + (lane & 15);
      const float b = bias[e];
      const int t0 = wr * 32 + m * 16 + (lane >> 4) * 4;
#pragma unroll
      for (int r = 0; r < 4; ++r) {
        const float logit = acc1[m][n][r] + acc2[m][n][r] * (1.0f / 2048.0f);
        scores[t0 + r][e] = 1.0f / (1.0f + expf(-logit)) + b;
      }
    }
  __syncthreads();

  // 8 tokens per wave, one active lane per token (64 total).
  if ((lane & 7) == 0) {
    const int t = wid * 8 + (lane >> 3);  // 0..63
    const float* sc = scores[t];

    float gmax[8];
#pragma unroll
    for (int g = 0; g < 8; ++g) {
      float mx = -1e30f;
      for (int j = 0; j < 32; ++j) mx = fmaxf(mx, sc[g * 32 + j]);
      gmax[g] = mx;
    }
    // top-4 groups (strict > keeps lowest index on ties, matching lax.top_k)
    unsigned selmask = 0;
    for (int it = 0; it < 4; ++it) {
      float best = -1e30f;
      int bi = 0;
      for (int g = 0; g < 8; ++g)
        if (!((selmask >> g) & 1) && gmax[g] > best) {
          best = gmax[g];
          bi = g;
        }
      selmask |= 1u << bi;
    }
    // stable top-8 over masked scores (masked-out groups contribute 0.0)
    float vals[8];
    int idx[8];
#pragma unroll
    for (int j = 0; j < 8; ++j) {
      vals[j] = -1e30f;
      idx[j] = 0;
    }
    for (int e = 0; e < 256; ++e) {
      const float v = ((selmask >> (e >> 5)) & 1) ? sc[e] : 0.0f;
      if (v > vals[7]) {
        int p = 7;
        while (p > 0 && v > vals[p - 1]) {
          vals[p] = vals[p - 1];
          idx[p] = idx[p - 1];
          --p;
        }
        vals[p] = v;
        idx[p] = e;
      }
    }
    float ssum = 0.0f;
#pragma unroll
    for (int j = 0; j < 8; ++j) ssum += vals[j];
    const float den = ssum + 1e-6f;
    const long tg = (long)tok0 + t;
#pragma unroll
    for (int j = 0; j < 8; ++j) {
      outw[tg * 8 + j] = vals[j] / den;
      outi[tg * 8 + j] = (float)idx[j];  // indices written as f32 values
    }
  }
}

extern "C" void kernel_launch(void* const* d_in, const int* in_sizes, int n_in,
                              void* d_out, int out_size, void* d_ws, size_t ws_size,
                              hipStream_t stream) {
  const float* X = (const float*)d_in[0];     // [16384,7168] f32
  const float* W = (const float*)d_in[1];     // [256,7168] f32
  const float* bias = (const float*)d_in[2];  // [256] f32

  _Float16* wblob = (_Float16*)d_ws;  // 7.34 MB fragment-major hi/lo blob

  float* outw = (float*)d_out;            // [16384,8]
  float* outi = outw + (size_t)TTOK * 8;  // [16384,8] as f32 values

  hipFuncSetAttribute((const void*)gate_kernel,
                      hipFuncAttributeMaxDynamicSharedMemorySize, LDS_BYTES);

  pack_w_kernel<<<dim3(HDIM / 32, EEXP / 16), 64, 0, stream>>>(W, wblob);
  gate_kernel<<<TTOK / BM, NTHR, LDS_BYTES, stream>>>(X, wblob, bias, outw, outi);
}